// Round 12
// baseline (198.035 us; speedup 1.0000x reference)
//
#include <hip/hip_runtime.h>
#include <math.h>

#define B_G   16
#define N_A   512
#define M_AT  8192
#define FD    128
#define HD    64
#define DD    16
#define SEIN  95
#define EHIN  159
#define NLUT  512
#define DMAXF 140.0f
#define NFB   1024  // src blocks in k_front: 8 atoms each, 32 lanes/atom

__device__ __forceinline__ float silu_f(float z) { return z / (1.f + __expf(-z)); }

// ================================================================ k_front
// blocks 0..1023: src MLP, 8 atoms each (4 waves x 2 atoms, 32 lanes/atom).
// 1024 blocks -> 4 blocks/CU x 4 waves = 16 waves/CU (was 8 at 16 lanes/atom).
// blocks 1024..1025: kernel-LUT (512 entries) + zero out[16].
__global__ __launch_bounds__(256) void k_front(
    const float* __restrict__ x,
    const float* __restrict__ g, const float* __restrict__ bb,
    const float* __restrict__ w1, const float* __restrict__ b1,
    const float* __restrict__ w2, const float* __restrict__ b2,
    const float* __restrict__ lng, const float* __restrict__ lnb,
    const float* __restrict__ k_screen,
    const float* __restrict__ kg_w1, const float* __restrict__ kg_b1,
    const float* __restrict__ kg_w2, const float* __restrict__ kg_b2,
    float* __restrict__ srcout, float* __restrict__ partials,
    float2* __restrict__ lut, float* __restrict__ out) {
  int t = threadIdx.x;

  if (blockIdx.x >= NFB) {
    // ---------------- LUT block ----------------
    int lb = blockIdx.x - NFB;
    __shared__ float w1l[320], b1l[32], w2l[32];
    if (lb == 0 && t < B_G) out[t] = 0.f;
    for (int idx = t; idx < 320; idx += 256) w1l[idx] = kg_w1[idx];
    if (t < 32) { b1l[t] = kg_b1[t]; w2l[t] = kg_w2[t]; }
    __syncthreads();
    int i = lb * 256 + t;
    float step = DMAXF / (float)(NLUT - 1);
    float ksv = k_screen[0];
    float screening = fmaxf(ksv, 0.f) + log1pf(expf(-fabsf(ksv)));
    float b2v = kg_b2[0];
    float vals[2];
#pragma unroll
    for (int e = 0; e < 2; ++e) {
      int ii = min(i + e, NLUT - 1);
      float d = (float)ii * step;
      float base = expf(-screening * d) / fmaxf(d, 1e-6f);
      float gin[10];
      gin[0] = d * (1.f / 5.0f);
      gin[1] = d * (1.f / 40.0f);
#pragma unroll
      for (int kk = 0; kk < 8; ++kk) {
        float u = d - (5.0f + 5.0f * (float)kk);
        gin[2 + kk] = expf(-(1.f / 25.f) * u * u);
      }
      float accv = 0.f;
      for (int h = 0; h < 32; ++h) {
        float z = b1l[h];
#pragma unroll
        for (int kk = 0; kk < 10; ++kk) z += gin[kk] * w1l[kk * 32 + h];
        accv += silu_f(z) * w2l[h];
      }
      vals[e] = base * (1.f + tanhf(accv + b2v));
    }
    lut[i] = make_float2(vals[0], vals[1] - vals[0]);
    return;
  }

  // ---------------- src block: 8 atoms, 32 lanes/atom ----------------
  int wave = t >> 6, lane = t & 63;
  int half = lane >> 5, l32 = lane & 31;   // atom within wave, lane within atom
  int a = wave * 2 + half;                 // atom index in block (0..7)
  int atom = blockIdx.x * 8 + a;

  __shared__ __align__(16) float xn[8 * 132];   // [a][128+4pad]  4.2 KB
  __shared__ __align__(16) float hb[8 * 68];    // [a][64+4pad]   2.2 KB
  __shared__ float psum[4][16];

  // LN(128): 32 lanes/atom, 4 dims each
  float4 xv = ((const float4*)(x + (size_t)atom * FD))[l32];
  float s = xv.x + xv.y + xv.z + xv.w;
  s += __shfl_xor(s, 1); s += __shfl_xor(s, 2); s += __shfl_xor(s, 4);
  s += __shfl_xor(s, 8); s += __shfl_xor(s, 16);
  float m = s * (1.f / 128.f);
  float d0 = xv.x - m, d1 = xv.y - m, d2 = xv.z - m, d3 = xv.w - m;
  float v2 = d0 * d0 + d1 * d1 + d2 * d2 + d3 * d3;
  v2 += __shfl_xor(v2, 1); v2 += __shfl_xor(v2, 2); v2 += __shfl_xor(v2, 4);
  v2 += __shfl_xor(v2, 8); v2 += __shfl_xor(v2, 16);
  float inv = rsqrtf(v2 * (1.f / 128.f) + 1e-5f);
  {
    float4 gv = ((const float4*)g)[l32];
    float4 bv = ((const float4*)bb)[l32];
    float4 o;
    o.x = d0 * inv * gv.x + bv.x;
    o.y = d1 * inv * gv.y + bv.y;
    o.z = d2 * inv * gv.z + bv.z;
    o.w = d3 * inv * gv.w + bv.w;
    *(float4*)&xn[a * 132 + l32 * 4] = o;
  }
  __syncthreads();

  // GEMM1 128->64: lane owns h = l32*2, l32*2+1
  float acc0 = 0.f, acc1 = 0.f;
  {
    const float* xnb = &xn[a * 132];
#pragma unroll 4
    for (int k = 0; k < FD; k += 4) {
      float4 xa = *(const float4*)(xnb + k);
      float2 wa = ((const float2*)(w1 + (size_t)(k + 0) * HD))[l32];
      float2 wbv = ((const float2*)(w1 + (size_t)(k + 1) * HD))[l32];
      float2 wc = ((const float2*)(w1 + (size_t)(k + 2) * HD))[l32];
      float2 wd = ((const float2*)(w1 + (size_t)(k + 3) * HD))[l32];
      acc0 += wa.x * xa.x; acc0 += wbv.x * xa.y; acc0 += wc.x * xa.z; acc0 += wd.x * xa.w;
      acc1 += wa.y * xa.x; acc1 += wbv.y * xa.y; acc1 += wc.y * xa.z; acc1 += wd.y * xa.w;
    }
    float2 bv = ((const float2*)b1)[l32];
    float2 ho;
    ho.x = silu_f(acc0 + bv.x);
    ho.y = silu_f(acc1 + bv.y);
    *(float2*)&hb[a * 68 + l32 * 2] = ho;
  }
  __syncthreads();

  // GEMM2 64->16: lane = (c = l32&15, hh = l32>>4); h-range split, xor-16 combine
  {
    int c = l32 & 15, hh = l32 >> 4;
    float acc2 = 0.f;
    const float* hbb = &hb[a * 68 + hh * 32];
#pragma unroll
    for (int h = 0; h < 32; h += 4) {
      float4 hv = *(const float4*)(hbb + h);
      int hg = hh * 32 + h;
      acc2 += w2[(hg + 0) * DD + c] * hv.x;
      acc2 += w2[(hg + 1) * DD + c] * hv.y;
      acc2 += w2[(hg + 2) * DD + c] * hv.z;
      acc2 += w2[(hg + 3) * DD + c] * hv.w;
    }
    acc2 += __shfl_xor(acc2, 16);     // combine the two h-halves
    float val = acc2 + b2[c];
    // LN(16) across the 16-channel group
    float sm = val;
    sm += __shfl_xor(sm, 1); sm += __shfl_xor(sm, 2); sm += __shfl_xor(sm, 4); sm += __shfl_xor(sm, 8);
    float mm = sm * (1.f / 16.f);
    float dv = val - mm;
    float vv = dv * dv;
    vv += __shfl_xor(vv, 1); vv += __shfl_xor(vv, 2); vv += __shfl_xor(vv, 4); vv += __shfl_xor(vv, 8);
    float iv = rsqrtf(vv * (1.f / 16.f) + 1e-5f);
    float ov = dv * iv * lng[c] + lnb[c];
    if ((lane & 31) < 16) srcout[(size_t)atom * DD + c] = ov;
    // per-block partial sum over atoms (for graph-mean neutralization)
    float lsum = ov;
    lsum += __shfl_xor(lsum, 32);     // sum wave's 2 atoms
    if (lane < 16) psum[wave][lane] = lsum;
  }
  __syncthreads();
  if (t < 16)
    partials[(size_t)blockIdx.x * 16 + t] =
        psum[0][t] + psum[1][t] + psum[2][t] + psum[3][t];
}

// ================================================================ k_pairs
// one wave per atom i; 4 atoms per 256-thread block (r5 geometry).
// NO ss staging: src (32 KB/graph) fits in L1; phase-2 reads are contiguous
// 1 KB/wave-instruction (coalesced, L1-hot). LDS ~8.3 KB. [verified r11: 187us total]
__global__ __launch_bounds__(256) void k_pairs(
    const float* __restrict__ pos, const float* __restrict__ src,
    const float2* __restrict__ lut, const float* __restrict__ partials,
    float* __restrict__ shell) {
  int gph = blockIdx.x >> 7;
  int blk = blockIdx.x & 127;
  int t = threadIdx.x, wave = t >> 6, lane = t & 63;
  int i_local = blk * 4 + wave;

  __shared__ __align__(16) float2 luts[NLUT];        // 4 KB
  __shared__ __align__(16) unsigned wb[4][N_A];      // 8 KB (w | tq low 3 bits)
  __shared__ float smean[16];

  const float* posg = pos + (size_t)gph * N_A * 3;
  const float* srcg = src + (size_t)gph * N_A * DD;

  if (t < NLUT / 2) ((float4*)luts)[t] = ((const float4*)lut)[t];
  if (t < 64) {  // wave 0: graph mean from partials (64 blocks/graph)
    int c = t & 15, grp = t >> 4;
    float sm = 0.f;
#pragma unroll
    for (int k = 0; k < 16; ++k)
      sm += partials[(size_t)(gph * 64 + grp * 16 + k) * 16 + c];
    sm += __shfl_xor(sm, 16); sm += __shfl_xor(sm, 32);
    if (t < 16) smean[c] = sm * (1.f / 512.f);
  }

  // own position straight from global (wave-uniform, cached)
  float px = posg[i_local * 3], py = posg[i_local * 3 + 1], pz = posg[i_local * 3 + 2];
  __syncthreads();

  float cnt[5] = {0,0,0,0,0}, sd[5] = {0,0,0,0,0}, sdd[5] = {0,0,0,0,0}, sw[5] = {0,0,0,0,0};
  const float lscale = (float)(NLUT - 1) / DMAXF;

#pragma unroll
  for (int it = 0; it < 8; ++it) {
    int jv = lane + it * 64;
    float qx = posg[jv * 3], qy = posg[jv * 3 + 1], qz = posg[jv * 3 + 2];
    float dx = px - qx, dy = py - qy, dz = pz - qz;
    float d2 = dx * dx + dy * dy + dz * dz + 1e-12f;
    float d = sqrtf(d2);
    bool valid = (jv != i_local) && (d >= 5.0f);
    int tq = (d >= 10.f) + (d >= 20.f) + (d >= 40.f) + (d >= 80.f);
    float xq = d * lscale;
    int i0 = min((int)xq, NLUT - 2);
    float f = xq - (float)i0;
    float2 L = luts[i0];
    float w = valid ? (L.x + L.y * f) : 0.f;
    wb[wave][jv] = (__float_as_uint(w) & ~7u) | (unsigned)tq;
    float dm = valid ? d : 0.f;
    float ddm = valid ? d * d : 0.f;
    float cm = valid ? 1.f : 0.f;
#pragma unroll
    for (int q = 0; q < 5; ++q) {
      bool mq = (tq == q);
      cnt[q] += mq ? cm : 0.f;
      sd[q]  += mq ? dm : 0.f;
      sdd[q] += mq ? ddm : 0.f;
      sw[q]  += mq ? w : 0.f;
    }
  }
#pragma unroll
  for (int q = 0; q < 5; ++q) {
#pragma unroll
    for (int o = 32; o > 0; o >>= 1) {
      cnt[q] += __shfl_xor(cnt[q], o);
      sd[q]  += __shfl_xor(sd[q], o);
      sdd[q] += __shfl_xor(sdd[q], o);
      sw[q]  += __shfl_xor(sw[q], o);
    }
  }
  __syncthreads();

  // phase 2: lane = (cq = lane&3, jlow = lane>>2); contiguous 1KB b128 reads
  // straight from global src (L1-resident after first touch).
  int cq = lane & 3, jlow = lane >> 2;
  float accq[5][4] = {};
  const float* ssb = srcg + jlow * DD + cq * 4;
  const unsigned* wbb = &wb[wave][jlow];
#pragma unroll
  for (int jj = 0; jj < 32; ++jj) {
    float4 sv = *(const float4*)(ssb + jj * 256);   // j = jj*16 + jlow
    unsigned u = wbb[jj * 16];
    int tq = (int)(u & 7u);
    float w = __uint_as_float(u & ~7u);
    float w0 = (tq == 0) ? w : 0.f;
    float w1_ = (tq == 1) ? w : 0.f;
    float w2_ = (tq == 2) ? w : 0.f;
    float w3_ = (tq == 3) ? w : 0.f;
    float w4_ = (tq == 4) ? w : 0.f;
    accq[0][0] += w0 * sv.x; accq[0][1] += w0 * sv.y; accq[0][2] += w0 * sv.z; accq[0][3] += w0 * sv.w;
    accq[1][0] += w1_ * sv.x; accq[1][1] += w1_ * sv.y; accq[1][2] += w1_ * sv.z; accq[1][3] += w1_ * sv.w;
    accq[2][0] += w2_ * sv.x; accq[2][1] += w2_ * sv.y; accq[2][2] += w2_ * sv.z; accq[2][3] += w2_ * sv.w;
    accq[3][0] += w3_ * sv.x; accq[3][1] += w3_ * sv.y; accq[3][2] += w3_ * sv.z; accq[3][3] += w3_ * sv.w;
    accq[4][0] += w4_ * sv.x; accq[4][1] += w4_ * sv.y; accq[4][2] += w4_ * sv.z; accq[4][3] += w4_ * sv.w;
  }
  // reduce across jlow (lane bits 2..5)
#pragma unroll
  for (int q = 0; q < 5; ++q)
#pragma unroll
    for (int i = 0; i < 4; ++i) {
      float v = accq[q][i];
      v += __shfl_xor(v, 4); v += __shfl_xor(v, 8); v += __shfl_xor(v, 16); v += __shfl_xor(v, 32);
      accq[q][i] = v;
    }

  float* shp = shell + (size_t)(gph * N_A + i_local) * SEIN;
  if (jlow == 0) {   // lanes 0..3 hold cq 0..3
#pragma unroll
    for (int q = 0; q < 5; ++q) {
      float denom = fmaxf(cnt[q], 1.f);
#pragma unroll
      for (int i = 0; i < 4; ++i) {
        int c = cq * 4 + i;
        shp[q * 19 + c] = (accq[q][i] - smean[c] * sw[q]) / denom;
      }
    }
  }
  if (lane < 5) {
    int q = lane;
    float denom = fmaxf(cnt[q], 1.f);
    shp[q * 19 + 16] = cnt[q];
    shp[q * 19 + 17] = sd[q] / denom;
    shp[q * 19 + 18] = sqrtf(sdd[q] / denom + 1e-12f);
  }
}

// ================================================================ k_tail
// fused se+eh MLPs; 16 atoms/block, 16 lanes/atom (4 waves x 4 atoms).
__global__ __launch_bounds__(256) void k_tail(
    const float* __restrict__ src, const float* __restrict__ shell,
    const float* __restrict__ partials,
    const float* __restrict__ se_ln_g, const float* __restrict__ se_ln_b,
    const float* __restrict__ se_w1, const float* __restrict__ se_b1,
    const float* __restrict__ se_w2, const float* __restrict__ se_b2,
    const float* __restrict__ eh_ln_g, const float* __restrict__ eh_ln_b,
    const float* __restrict__ eh_w1, const float* __restrict__ eh_b1,
    const float* __restrict__ eh_w2, const float* __restrict__ eh_b2,
    const float* __restrict__ far_gate, const float* __restrict__ energy_scale,
    float* __restrict__ out) {
  int t = threadIdx.x, wave = t >> 6, lane = t & 63;
  int ag = lane >> 4, l16 = lane & 15;
  int a = wave * 4 + ag;                 // atom in block (0..15)
  int aB = blockIdx.x * 16;
  int gph = aB >> 9;

  __shared__ __align__(16) float ein[16 * 160];  // [a][159+pad]  10 KB
  __shared__ __align__(16) float shn[16 * 96];   // [a][95+pad]    6 KB
  __shared__ __align__(16) float hb[16 * 68];    // [a][64+pad]  4.3 KB
  __shared__ float smean[16];
  __shared__ float redv[4];

  if (t < 64) {  // wave 0: graph mean from partials (64 blocks/graph)
    int c = t & 15, grp = t >> 4;
    float sm = 0.f;
#pragma unroll
    for (int k = 0; k < 16; ++k)
      sm += partials[(size_t)(gph * 64 + grp * 16 + k) * 16 + c];
    sm += __shfl_xor(sm, 16); sm += __shfl_xor(sm, 32);
    if (t < 16) smean[c] = sm * (1.f / 512.f);
  }

  // stage raw shell -> ein cols 64..158 per atom (coalesced, magic div by 95)
  const float* shg = shell + (size_t)aB * SEIN;
  for (int idx = t; idx < 16 * SEIN; idx += 256) {
    unsigned a_loc = ((unsigned)idx * 690u) >> 16;
    int kk = idx - (int)a_loc * SEIN;
    ein[a_loc * 160 + 64 + kk] = shg[idx];
  }
  __syncthreads();

  // LN(95) -> shn
  {
    float s1 = 0.f, sq = 0.f;
    const float* eb = &ein[a * 160 + 64];
#pragma unroll
    for (int i = 0; i < 6; ++i) {
      int k = l16 * 6 + i;
      if (k < SEIN) { float v = eb[k]; s1 += v; sq += v * v; }
    }
    s1 += __shfl_xor(s1, 1); s1 += __shfl_xor(s1, 2); s1 += __shfl_xor(s1, 4); s1 += __shfl_xor(s1, 8);
    sq += __shfl_xor(sq, 1); sq += __shfl_xor(sq, 2); sq += __shfl_xor(sq, 4); sq += __shfl_xor(sq, 8);
    float m = s1 * (1.f / (float)SEIN);
    float var = sq * (1.f / (float)SEIN) - m * m;
    float inv = rsqrtf(var + 1e-5f);
#pragma unroll
    for (int i = 0; i < 6; ++i) {
      int k = l16 * 6 + i;
      if (k < SEIN)
        shn[a * 96 + k] = (eb[k] - m) * inv * se_ln_g[k] + se_ln_b[k];
    }
  }
  __syncthreads();

  int h0 = l16 * 4;
  // se GEMM1 95->64: lane owns h = l16*4..+3
  {
    float acc[4] = {0.f, 0.f, 0.f, 0.f};
    const float* sb = &shn[a * 96];
#pragma unroll 4
    for (int k = 0; k < 92; k += 4) {
      float4 xa = *(const float4*)(sb + k);
      float4 wa = ((const float4*)(se_w1 + (size_t)(k + 0) * HD))[l16];
      float4 wbv = ((const float4*)(se_w1 + (size_t)(k + 1) * HD))[l16];
      float4 wc = ((const float4*)(se_w1 + (size_t)(k + 2) * HD))[l16];
      float4 wd = ((const float4*)(se_w1 + (size_t)(k + 3) * HD))[l16];
      acc[0] += wa.x * xa.x; acc[0] += wbv.x * xa.y; acc[0] += wc.x * xa.z; acc[0] += wd.x * xa.w;
      acc[1] += wa.y * xa.x; acc[1] += wbv.y * xa.y; acc[1] += wc.y * xa.z; acc[1] += wd.y * xa.w;
      acc[2] += wa.z * xa.x; acc[2] += wbv.z * xa.y; acc[2] += wc.z * xa.z; acc[2] += wd.z * xa.w;
      acc[3] += wa.w * xa.x; acc[3] += wbv.w * xa.y; acc[3] += wc.w * xa.z; acc[3] += wd.w * xa.w;
    }
#pragma unroll
    for (int k = 92; k < SEIN; ++k) {
      float xa = sb[k];
      float4 wa = ((const float4*)(se_w1 + (size_t)k * HD))[l16];
      acc[0] += wa.x * xa; acc[1] += wa.y * xa; acc[2] += wa.z * xa; acc[3] += wa.w * xa;
    }
    float4 bv = ((const float4*)se_b1)[l16];
    float4 ho;
    ho.x = silu_f(acc[0] + bv.x); ho.y = silu_f(acc[1] + bv.y);
    ho.z = silu_f(acc[2] + bv.z); ho.w = silu_f(acc[3] + bv.w);
    *(float4*)&hb[a * 68 + h0] = ho;
  }
  __syncthreads();

  // se GEMM2 64->16 -> emb; build ein cols 0..63
  {
    float acc2 = 0.f;
    const float* hbb = &hb[a * 68];
#pragma unroll
    for (int h = 0; h < HD; h += 4) {
      float4 hv = *(const float4*)(hbb + h);
      acc2 += se_w2[(h + 0) * DD + l16] * hv.x;
      acc2 += se_w2[(h + 1) * DD + l16] * hv.y;
      acc2 += se_w2[(h + 2) * DD + l16] * hv.z;
      acc2 += se_w2[(h + 3) * DD + l16] * hv.w;
    }
    float ev = acc2 + se_b2[l16];
    float sv = src[(size_t)(aB + a) * DD + l16] - smean[l16];
    ein[a * 160 + l16] = sv;
    ein[a * 160 + 16 + l16] = ev;
    ein[a * 160 + 32 + l16] = sv * ev;
    ein[a * 160 + 48 + l16] = sv - ev;
  }
  __syncthreads();

  // LN(159) in-place
  {
    float s1 = 0.f, sq = 0.f;
    float* eb = &ein[a * 160];
#pragma unroll
    for (int i = 0; i < 10; ++i) {
      int k = l16 * 10 + i;
      if (k < EHIN) { float v = eb[k]; s1 += v; sq += v * v; }
    }
    s1 += __shfl_xor(s1, 1); s1 += __shfl_xor(s1, 2); s1 += __shfl_xor(s1, 4); s1 += __shfl_xor(s1, 8);
    sq += __shfl_xor(sq, 1); sq += __shfl_xor(sq, 2); sq += __shfl_xor(sq, 4); sq += __shfl_xor(sq, 8);
    float m = s1 * (1.f / (float)EHIN);
    float var = sq * (1.f / (float)EHIN) - m * m;
    float inv = rsqrtf(var + 1e-5f);
#pragma unroll
    for (int i = 0; i < 10; ++i) {
      int k = l16 * 10 + i;
      if (k < EHIN)
        eb[k] = (eb[k] - m) * inv * eh_ln_g[k] + eh_ln_b[k];
    }
  }
  __syncthreads();

  // eh GEMM 159->64, dot with eh_w2, reduce
  {
    float acc[4] = {0.f, 0.f, 0.f, 0.f};
    const float* eb = &ein[a * 160];
#pragma unroll 4
    for (int k = 0; k < 156; k += 4) {
      float4 xa = *(const float4*)(eb + k);
      float4 wa = ((const float4*)(eh_w1 + (size_t)(k + 0) * HD))[l16];
      float4 wbv = ((const float4*)(eh_w1 + (size_t)(k + 1) * HD))[l16];
      float4 wc = ((const float4*)(eh_w1 + (size_t)(k + 2) * HD))[l16];
      float4 wd = ((const float4*)(eh_w1 + (size_t)(k + 3) * HD))[l16];
      acc[0] += wa.x * xa.x; acc[0] += wbv.x * xa.y; acc[0] += wc.x * xa.z; acc[0] += wd.x * xa.w;
      acc[1] += wa.y * xa.x; acc[1] += wbv.y * xa.y; acc[1] += wc.y * xa.z; acc[1] += wd.y * xa.w;
      acc[2] += wa.z * xa.x; acc[2] += wbv.z * xa.y; acc[2] += wc.z * xa.z; acc[2] += wd.z * xa.w;
      acc[3] += wa.w * xa.x; acc[3] += wbv.w * xa.y; acc[3] += wc.w * xa.z; acc[3] += wd.w * xa.w;
    }
#pragma unroll
    for (int k = 156; k < EHIN; ++k) {
      float xa = eb[k];
      float4 wa = ((const float4*)(eh_w1 + (size_t)k * HD))[l16];
      acc[0] += wa.x * xa; acc[1] += wa.y * xa; acc[2] += wa.z * xa; acc[3] += wa.w * xa;
    }
    float4 b1v = ((const float4*)eh_b1)[l16];
    float4 w2v = ((const float4*)eh_w2)[l16];
    float pa = silu_f(acc[0] + b1v.x) * w2v.x + silu_f(acc[1] + b1v.y) * w2v.y
             + silu_f(acc[2] + b1v.z) * w2v.z + silu_f(acc[3] + b1v.w) * w2v.w;
    pa += __shfl_xor(pa, 1); pa += __shfl_xor(pa, 2); pa += __shfl_xor(pa, 4); pa += __shfl_xor(pa, 8);
    pa += __shfl_xor(pa, 16); pa += __shfl_xor(pa, 32);  // sum wave's 4 atoms
    if (lane == 0) redv[wave] = pa + 4.f * eh_b2[0];
  }
  __syncthreads();
  if (t == 0) {
    float tot = redv[0] + redv[1] + redv[2] + redv[3];
    atomicAdd(&out[gph], tot * tanhf(far_gate[0]) * expf(energy_scale[0]));
  }
}

// ================================================================ launch
extern "C" void kernel_launch(void* const* d_in, const int* in_sizes, int n_in,
                              void* d_out, int out_size, void* d_ws, size_t ws_size,
                              hipStream_t stream) {
  const float* x         = (const float*)d_in[0];
  const float* pos       = (const float*)d_in[1];
  const float* in_ln_g   = (const float*)d_in[4];
  const float* in_ln_b   = (const float*)d_in[5];
  const float* src_w1    = (const float*)d_in[6];
  const float* src_b1    = (const float*)d_in[7];
  const float* src_w2    = (const float*)d_in[8];
  const float* src_b2    = (const float*)d_in[9];
  const float* src_ln_g  = (const float*)d_in[10];
  const float* src_ln_b  = (const float*)d_in[11];
  const float* se_ln_g   = (const float*)d_in[12];
  const float* se_ln_b   = (const float*)d_in[13];
  const float* se_w1     = (const float*)d_in[14];
  const float* se_b1     = (const float*)d_in[15];
  const float* se_w2     = (const float*)d_in[16];
  const float* se_b2     = (const float*)d_in[17];
  const float* eh_ln_g   = (const float*)d_in[18];
  const float* eh_ln_b   = (const float*)d_in[19];
  const float* eh_w1     = (const float*)d_in[20];
  const float* eh_b1     = (const float*)d_in[21];
  const float* eh_w2     = (const float*)d_in[22];
  const float* eh_b2     = (const float*)d_in[23];
  const float* k_screen  = (const float*)d_in[24];
  const float* kg_w1     = (const float*)d_in[25];
  const float* kg_b1     = (const float*)d_in[26];
  const float* kg_w2     = (const float*)d_in[27];
  const float* kg_b2     = (const float*)d_in[28];
  const float* far_gate  = (const float*)d_in[29];
  const float* en_scale  = (const float*)d_in[30];
  float* out = (float*)d_out;

  float* ws_src   = (float*)d_ws;                            // M*16
  float* ws_shell = ws_src + (size_t)M_AT * DD;              // M*95
  float* ws_part  = ws_shell + (size_t)M_AT * SEIN;          // 1024*16
  float2* ws_lut  = (float2*)(ws_part + NFB * 16);           // NLUT float2

  k_front<<<NFB + 2, 256, 0, stream>>>(x, in_ln_g, in_ln_b, src_w1, src_b1,
                                       src_w2, src_b2, src_ln_g, src_ln_b,
                                       k_screen, kg_w1, kg_b1, kg_w2, kg_b2,
                                       ws_src, ws_part, ws_lut, out);
  k_pairs<<<B_G * (N_A / 4), 256, 0, stream>>>(pos, ws_src, ws_lut, ws_part, ws_shell);
  k_tail<<<M_AT / 16, 256, 0, stream>>>(ws_src, ws_shell, ws_part,
                                        se_ln_g, se_ln_b, se_w1, se_b1, se_w2, se_b2,
                                        eh_ln_g, eh_ln_b, eh_w1, eh_b1, eh_w2, eh_b2,
                                        far_gate, en_scale, out);
}

// Round 13
// 183.935 us; speedup vs baseline: 1.0767x; 1.0767x over previous
//
#include <hip/hip_runtime.h>
#include <math.h>

#define B_G   16
#define N_A   512
#define M_AT  8192
#define FD    128
#define HD    64
#define DD    16
#define SEIN  95
#define EHIN  159
#define NLUT  512
#define DMAXF 140.0f
#define NFB   512   // src blocks in k_front: 16 atoms each, 16 lanes/atom

__device__ __forceinline__ float silu_f(float z) { return z / (1.f + __expf(-z)); }

// ================================================================ k_front
// blocks 0..511: src MLP, 16 atoms each (4 waves x 4 atoms, 16 lanes/atom).
// blocks 512..513: kernel-LUT (512 entries) + zero out[16].
__global__ __launch_bounds__(256) void k_front(
    const float* __restrict__ x,
    const float* __restrict__ g, const float* __restrict__ bb,
    const float* __restrict__ w1, const float* __restrict__ b1,
    const float* __restrict__ w2, const float* __restrict__ b2,
    const float* __restrict__ lng, const float* __restrict__ lnb,
    const float* __restrict__ k_screen,
    const float* __restrict__ kg_w1, const float* __restrict__ kg_b1,
    const float* __restrict__ kg_w2, const float* __restrict__ kg_b2,
    float* __restrict__ srcout, float* __restrict__ partials,
    float2* __restrict__ lut, float* __restrict__ out) {
  int t = threadIdx.x;

  if (blockIdx.x >= NFB) {
    // ---------------- LUT block ----------------
    int lb = blockIdx.x - NFB;
    __shared__ float w1l[320], b1l[32], w2l[32];
    if (lb == 0 && t < B_G) out[t] = 0.f;
    for (int idx = t; idx < 320; idx += 256) w1l[idx] = kg_w1[idx];
    if (t < 32) { b1l[t] = kg_b1[t]; w2l[t] = kg_w2[t]; }
    __syncthreads();
    int i = lb * 256 + t;
    float step = DMAXF / (float)(NLUT - 1);
    float ksv = k_screen[0];
    float screening = fmaxf(ksv, 0.f) + log1pf(expf(-fabsf(ksv)));
    float b2v = kg_b2[0];
    float vals[2];
#pragma unroll
    for (int e = 0; e < 2; ++e) {
      int ii = min(i + e, NLUT - 1);
      float d = (float)ii * step;
      float base = expf(-screening * d) / fmaxf(d, 1e-6f);
      float gin[10];
      gin[0] = d * (1.f / 5.0f);
      gin[1] = d * (1.f / 40.0f);
#pragma unroll
      for (int kk = 0; kk < 8; ++kk) {
        float u = d - (5.0f + 5.0f * (float)kk);
        gin[2 + kk] = expf(-(1.f / 25.f) * u * u);
      }
      float accv = 0.f;
      for (int h = 0; h < 32; ++h) {
        float z = b1l[h];
#pragma unroll
        for (int kk = 0; kk < 10; ++kk) z += gin[kk] * w1l[kk * 32 + h];
        accv += silu_f(z) * w2l[h];
      }
      vals[e] = base * (1.f + tanhf(accv + b2v));
    }
    lut[i] = make_float2(vals[0], vals[1] - vals[0]);
    return;
  }

  // ---------------- src block: 16 atoms, 16 lanes/atom ----------------
  int wave = t >> 6, lane = t & 63;
  int ag = lane >> 4, l16 = lane & 15;     // atom-group within wave, lane within group
  int a = wave * 4 + ag;                   // atom index in block (0..15)
  int atom = blockIdx.x * 16 + a;

  __shared__ __align__(16) float xn[16 * 132];  // [a][128+4pad]  8.4 KB
  __shared__ __align__(16) float hb[16 * 68];   // [a][64+4pad]   4.3 KB
  __shared__ float psum[4][16];

  // LN(128): 16 lanes/atom, 8 dims each
  float xr[8];
  {
    const float4* xp = (const float4*)(x + (size_t)atom * FD + l16 * 8);
    float4 v0 = xp[0], v1 = xp[1];
    xr[0] = v0.x; xr[1] = v0.y; xr[2] = v0.z; xr[3] = v0.w;
    xr[4] = v1.x; xr[5] = v1.y; xr[6] = v1.z; xr[7] = v1.w;
  }
  float s = 0.f;
#pragma unroll
  for (int i = 0; i < 8; ++i) s += xr[i];
  s += __shfl_xor(s, 1); s += __shfl_xor(s, 2); s += __shfl_xor(s, 4); s += __shfl_xor(s, 8);
  float m = s * (1.f / 128.f);
  float v2 = 0.f;
#pragma unroll
  for (int i = 0; i < 8; ++i) { float d = xr[i] - m; v2 += d * d; }
  v2 += __shfl_xor(v2, 1); v2 += __shfl_xor(v2, 2); v2 += __shfl_xor(v2, 4); v2 += __shfl_xor(v2, 8);
  float inv = rsqrtf(v2 * (1.f / 128.f) + 1e-5f);
  {
    int kb = l16 * 8;
    float4 gv0 = ((const float4*)g)[l16 * 2], gv1 = ((const float4*)g)[l16 * 2 + 1];
    float4 bv0 = ((const float4*)bb)[l16 * 2], bv1 = ((const float4*)bb)[l16 * 2 + 1];
    float4 o0, o1;
    o0.x = (xr[0] - m) * inv * gv0.x + bv0.x;
    o0.y = (xr[1] - m) * inv * gv0.y + bv0.y;
    o0.z = (xr[2] - m) * inv * gv0.z + bv0.z;
    o0.w = (xr[3] - m) * inv * gv0.w + bv0.w;
    o1.x = (xr[4] - m) * inv * gv1.x + bv1.x;
    o1.y = (xr[5] - m) * inv * gv1.y + bv1.y;
    o1.z = (xr[6] - m) * inv * gv1.z + bv1.z;
    o1.w = (xr[7] - m) * inv * gv1.w + bv1.w;
    *(float4*)&xn[a * 132 + kb] = o0;
    *(float4*)&xn[a * 132 + kb + 4] = o1;
  }
  __syncthreads();

  // GEMM1 128->64: lane owns h = l16*4..+3 of its atom
  float acc[4] = {0.f, 0.f, 0.f, 0.f};
  {
    const float* xnb = &xn[a * 132];
#pragma unroll 4
    for (int k = 0; k < FD; k += 4) {
      float4 xa = *(const float4*)(xnb + k);
      float4 wa = ((const float4*)(w1 + (size_t)(k + 0) * HD))[l16];
      float4 wbv = ((const float4*)(w1 + (size_t)(k + 1) * HD))[l16];
      float4 wc = ((const float4*)(w1 + (size_t)(k + 2) * HD))[l16];
      float4 wd = ((const float4*)(w1 + (size_t)(k + 3) * HD))[l16];
      acc[0] += wa.x * xa.x; acc[0] += wbv.x * xa.y; acc[0] += wc.x * xa.z; acc[0] += wd.x * xa.w;
      acc[1] += wa.y * xa.x; acc[1] += wbv.y * xa.y; acc[1] += wc.y * xa.z; acc[1] += wd.y * xa.w;
      acc[2] += wa.z * xa.x; acc[2] += wbv.z * xa.y; acc[2] += wc.z * xa.z; acc[2] += wd.z * xa.w;
      acc[3] += wa.w * xa.x; acc[3] += wbv.w * xa.y; acc[3] += wc.w * xa.z; acc[3] += wd.w * xa.w;
    }
    float4 bv = ((const float4*)b1)[l16];
    float4 ho;
    ho.x = silu_f(acc[0] + bv.x); ho.y = silu_f(acc[1] + bv.y);
    ho.z = silu_f(acc[2] + bv.z); ho.w = silu_f(acc[3] + bv.w);
    *(float4*)&hb[a * 68 + l16 * 4] = ho;
  }
  __syncthreads();

  // GEMM2 64->16: lane owns output channel c = l16
  {
    float acc2 = 0.f;
    const float* hbb = &hb[a * 68];
#pragma unroll
    for (int h = 0; h < HD; h += 4) {
      float4 hv = *(const float4*)(hbb + h);
      acc2 += w2[(h + 0) * DD + l16] * hv.x;
      acc2 += w2[(h + 1) * DD + l16] * hv.y;
      acc2 += w2[(h + 2) * DD + l16] * hv.z;
      acc2 += w2[(h + 3) * DD + l16] * hv.w;
    }
    float val = acc2 + b2[l16];
    // LN(16) across the 16-lane group
    float sm = val;
    sm += __shfl_xor(sm, 1); sm += __shfl_xor(sm, 2); sm += __shfl_xor(sm, 4); sm += __shfl_xor(sm, 8);
    float mm = sm * (1.f / 16.f);
    float dv = val - mm;
    float vv = dv * dv;
    vv += __shfl_xor(vv, 1); vv += __shfl_xor(vv, 2); vv += __shfl_xor(vv, 4); vv += __shfl_xor(vv, 8);
    float iv = rsqrtf(vv * (1.f / 16.f) + 1e-5f);
    float ov = dv * iv * lng[l16] + lnb[l16];
    srcout[(size_t)atom * DD + l16] = ov;
    // per-block partial sum over atoms (for graph-mean neutralization)
    float lsum = ov;
    lsum += __shfl_xor(lsum, 16); lsum += __shfl_xor(lsum, 32);  // sum wave's 4 atoms
    if (lane < 16) psum[wave][l16] = lsum;
  }
  __syncthreads();
  if (t < 16)
    partials[(size_t)blockIdx.x * 16 + t] =
        psum[0][t] + psum[1][t] + psum[2][t] + psum[3][t];
}

// ================================================================ k_pairs
// one wave per atom i; 4 atoms per 256-thread block (r5 geometry, best).
// NO ss staging: src (32 KB/graph) fits in L1; phase-2 reads are contiguous
// 1 KB/wave-instruction (coalesced, L1-hot). LDS ~8.3 KB. [verified r11: 187us total]
__global__ __launch_bounds__(256) void k_pairs(
    const float* __restrict__ pos, const float* __restrict__ src,
    const float2* __restrict__ lut, const float* __restrict__ partials,
    float* __restrict__ shell) {
  int gph = blockIdx.x >> 7;
  int blk = blockIdx.x & 127;
  int t = threadIdx.x, wave = t >> 6, lane = t & 63;
  int i_local = blk * 4 + wave;

  __shared__ __align__(16) float2 luts[NLUT];        // 4 KB
  __shared__ __align__(16) unsigned wb[4][N_A];      // 8 KB (w | tq low 3 bits)
  __shared__ float smean[16];

  const float* posg = pos + (size_t)gph * N_A * 3;
  const float* srcg = src + (size_t)gph * N_A * DD;

  if (t < NLUT / 2) ((float4*)luts)[t] = ((const float4*)lut)[t];
  if (t < 64) {  // wave 0: graph mean from partials (32 blocks/graph)
    int c = t & 15, grp = t >> 4;
    float sm = 0.f;
#pragma unroll
    for (int k = 0; k < 8; ++k)
      sm += partials[(size_t)(gph * 32 + grp * 8 + k) * 16 + c];
    sm += __shfl_xor(sm, 16); sm += __shfl_xor(sm, 32);
    if (t < 16) smean[c] = sm * (1.f / 512.f);
  }

  // own position straight from global (wave-uniform, cached)
  float px = posg[i_local * 3], py = posg[i_local * 3 + 1], pz = posg[i_local * 3 + 2];
  __syncthreads();

  float cnt[5] = {0,0,0,0,0}, sd[5] = {0,0,0,0,0}, sdd[5] = {0,0,0,0,0}, sw[5] = {0,0,0,0,0};
  const float lscale = (float)(NLUT - 1) / DMAXF;

#pragma unroll
  for (int it = 0; it < 8; ++it) {
    int jv = lane + it * 64;
    float qx = posg[jv * 3], qy = posg[jv * 3 + 1], qz = posg[jv * 3 + 2];
    float dx = px - qx, dy = py - qy, dz = pz - qz;
    float d2 = dx * dx + dy * dy + dz * dz + 1e-12f;
    float d = sqrtf(d2);
    bool valid = (jv != i_local) && (d >= 5.0f);
    int tq = (d >= 10.f) + (d >= 20.f) + (d >= 40.f) + (d >= 80.f);
    float xq = d * lscale;
    int i0 = min((int)xq, NLUT - 2);
    float f = xq - (float)i0;
    float2 L = luts[i0];
    float w = valid ? (L.x + L.y * f) : 0.f;
    wb[wave][jv] = (__float_as_uint(w) & ~7u) | (unsigned)tq;
    float dm = valid ? d : 0.f;
    float ddm = valid ? d * d : 0.f;
    float cm = valid ? 1.f : 0.f;
#pragma unroll
    for (int q = 0; q < 5; ++q) {
      bool mq = (tq == q);
      cnt[q] += mq ? cm : 0.f;
      sd[q]  += mq ? dm : 0.f;
      sdd[q] += mq ? ddm : 0.f;
      sw[q]  += mq ? w : 0.f;
    }
  }
#pragma unroll
  for (int q = 0; q < 5; ++q) {
#pragma unroll
    for (int o = 32; o > 0; o >>= 1) {
      cnt[q] += __shfl_xor(cnt[q], o);
      sd[q]  += __shfl_xor(sd[q], o);
      sdd[q] += __shfl_xor(sdd[q], o);
      sw[q]  += __shfl_xor(sw[q], o);
    }
  }
  __syncthreads();

  // phase 2: lane = (cq = lane&3, jlow = lane>>2); contiguous 1KB b128 reads
  // straight from global src (L1-resident after first touch).
  int cq = lane & 3, jlow = lane >> 2;
  float accq[5][4] = {};
  const float* ssb = srcg + jlow * DD + cq * 4;
  const unsigned* wbb = &wb[wave][jlow];
#pragma unroll
  for (int jj = 0; jj < 32; ++jj) {
    float4 sv = *(const float4*)(ssb + jj * 256);   // j = jj*16 + jlow
    unsigned u = wbb[jj * 16];
    int tq = (int)(u & 7u);
    float w = __uint_as_float(u & ~7u);
    float w0 = (tq == 0) ? w : 0.f;
    float w1_ = (tq == 1) ? w : 0.f;
    float w2_ = (tq == 2) ? w : 0.f;
    float w3_ = (tq == 3) ? w : 0.f;
    float w4_ = (tq == 4) ? w : 0.f;
    accq[0][0] += w0 * sv.x; accq[0][1] += w0 * sv.y; accq[0][2] += w0 * sv.z; accq[0][3] += w0 * sv.w;
    accq[1][0] += w1_ * sv.x; accq[1][1] += w1_ * sv.y; accq[1][2] += w1_ * sv.z; accq[1][3] += w1_ * sv.w;
    accq[2][0] += w2_ * sv.x; accq[2][1] += w2_ * sv.y; accq[2][2] += w2_ * sv.z; accq[2][3] += w2_ * sv.w;
    accq[3][0] += w3_ * sv.x; accq[3][1] += w3_ * sv.y; accq[3][2] += w3_ * sv.z; accq[3][3] += w3_ * sv.w;
    accq[4][0] += w4_ * sv.x; accq[4][1] += w4_ * sv.y; accq[4][2] += w4_ * sv.z; accq[4][3] += w4_ * sv.w;
  }
  // reduce across jlow (lane bits 2..5)
#pragma unroll
  for (int q = 0; q < 5; ++q)
#pragma unroll
    for (int i = 0; i < 4; ++i) {
      float v = accq[q][i];
      v += __shfl_xor(v, 4); v += __shfl_xor(v, 8); v += __shfl_xor(v, 16); v += __shfl_xor(v, 32);
      accq[q][i] = v;
    }

  float* shp = shell + (size_t)(gph * N_A + i_local) * SEIN;
  if (jlow == 0) {   // lanes 0..3 hold cq 0..3
#pragma unroll
    for (int q = 0; q < 5; ++q) {
      float denom = fmaxf(cnt[q], 1.f);
#pragma unroll
      for (int i = 0; i < 4; ++i) {
        int c = cq * 4 + i;
        shp[q * 19 + c] = (accq[q][i] - smean[c] * sw[q]) / denom;
      }
    }
  }
  if (lane < 5) {
    int q = lane;
    float denom = fmaxf(cnt[q], 1.f);
    shp[q * 19 + 16] = cnt[q];
    shp[q * 19 + 17] = sd[q] / denom;
    shp[q * 19 + 18] = sqrtf(sdd[q] / denom + 1e-12f);
  }
}

// ================================================================ k_tail
// fused se+eh MLPs; 16 atoms/block, 16 lanes/atom (4 waves x 4 atoms).
__global__ __launch_bounds__(256) void k_tail(
    const float* __restrict__ src, const float* __restrict__ shell,
    const float* __restrict__ partials,
    const float* __restrict__ se_ln_g, const float* __restrict__ se_ln_b,
    const float* __restrict__ se_w1, const float* __restrict__ se_b1,
    const float* __restrict__ se_w2, const float* __restrict__ se_b2,
    const float* __restrict__ eh_ln_g, const float* __restrict__ eh_ln_b,
    const float* __restrict__ eh_w1, const float* __restrict__ eh_b1,
    const float* __restrict__ eh_w2, const float* __restrict__ eh_b2,
    const float* __restrict__ far_gate, const float* __restrict__ energy_scale,
    float* __restrict__ out) {
  int t = threadIdx.x, wave = t >> 6, lane = t & 63;
  int ag = lane >> 4, l16 = lane & 15;
  int a = wave * 4 + ag;                 // atom in block (0..15)
  int aB = blockIdx.x * 16;
  int gph = aB >> 9;

  __shared__ __align__(16) float ein[16 * 160];  // [a][159+pad]  10 KB
  __shared__ __align__(16) float shn[16 * 96];   // [a][95+pad]    6 KB
  __shared__ __align__(16) float hb[16 * 68];    // [a][64+pad]  4.3 KB
  __shared__ float smean[16];
  __shared__ float redv[4];

  if (t < 64) {  // wave 0: graph mean from partials (32 blocks/graph)
    int c = t & 15, grp = t >> 4;
    float sm = 0.f;
#pragma unroll
    for (int k = 0; k < 8; ++k)
      sm += partials[(size_t)(gph * 32 + grp * 8 + k) * 16 + c];
    sm += __shfl_xor(sm, 16); sm += __shfl_xor(sm, 32);
    if (t < 16) smean[c] = sm * (1.f / 512.f);
  }

  // stage raw shell -> ein cols 64..158 per atom (coalesced, magic div by 95)
  const float* shg = shell + (size_t)aB * SEIN;
  for (int idx = t; idx < 16 * SEIN; idx += 256) {
    unsigned a_loc = ((unsigned)idx * 690u) >> 16;
    int kk = idx - (int)a_loc * SEIN;
    ein[a_loc * 160 + 64 + kk] = shg[idx];
  }
  __syncthreads();

  // LN(95) -> shn
  {
    float s1 = 0.f, sq = 0.f;
    const float* eb = &ein[a * 160 + 64];
#pragma unroll
    for (int i = 0; i < 6; ++i) {
      int k = l16 * 6 + i;
      if (k < SEIN) { float v = eb[k]; s1 += v; sq += v * v; }
    }
    s1 += __shfl_xor(s1, 1); s1 += __shfl_xor(s1, 2); s1 += __shfl_xor(s1, 4); s1 += __shfl_xor(s1, 8);
    sq += __shfl_xor(sq, 1); sq += __shfl_xor(sq, 2); sq += __shfl_xor(sq, 4); sq += __shfl_xor(sq, 8);
    float m = s1 * (1.f / (float)SEIN);
    float var = sq * (1.f / (float)SEIN) - m * m;
    float inv = rsqrtf(var + 1e-5f);
#pragma unroll
    for (int i = 0; i < 6; ++i) {
      int k = l16 * 6 + i;
      if (k < SEIN)
        shn[a * 96 + k] = (eb[k] - m) * inv * se_ln_g[k] + se_ln_b[k];
    }
  }
  __syncthreads();

  int h0 = l16 * 4;
  // se GEMM1 95->64: lane owns h = l16*4..+3
  {
    float acc[4] = {0.f, 0.f, 0.f, 0.f};
    const float* sb = &shn[a * 96];
#pragma unroll 4
    for (int k = 0; k < 92; k += 4) {
      float4 xa = *(const float4*)(sb + k);
      float4 wa = ((const float4*)(se_w1 + (size_t)(k + 0) * HD))[l16];
      float4 wbv = ((const float4*)(se_w1 + (size_t)(k + 1) * HD))[l16];
      float4 wc = ((const float4*)(se_w1 + (size_t)(k + 2) * HD))[l16];
      float4 wd = ((const float4*)(se_w1 + (size_t)(k + 3) * HD))[l16];
      acc[0] += wa.x * xa.x; acc[0] += wbv.x * xa.y; acc[0] += wc.x * xa.z; acc[0] += wd.x * xa.w;
      acc[1] += wa.y * xa.x; acc[1] += wbv.y * xa.y; acc[1] += wc.y * xa.z; acc[1] += wd.y * xa.w;
      acc[2] += wa.z * xa.x; acc[2] += wbv.z * xa.y; acc[2] += wc.z * xa.z; acc[2] += wd.z * xa.w;
      acc[3] += wa.w * xa.x; acc[3] += wbv.w * xa.y; acc[3] += wc.w * xa.z; acc[3] += wd.w * xa.w;
    }
#pragma unroll
    for (int k = 92; k < SEIN; ++k) {
      float xa = sb[k];
      float4 wa = ((const float4*)(se_w1 + (size_t)k * HD))[l16];
      acc[0] += wa.x * xa; acc[1] += wa.y * xa; acc[2] += wa.z * xa; acc[3] += wa.w * xa;
    }
    float4 bv = ((const float4*)se_b1)[l16];
    float4 ho;
    ho.x = silu_f(acc[0] + bv.x); ho.y = silu_f(acc[1] + bv.y);
    ho.z = silu_f(acc[2] + bv.z); ho.w = silu_f(acc[3] + bv.w);
    *(float4*)&hb[a * 68 + h0] = ho;
  }
  __syncthreads();

  // se GEMM2 64->16 -> emb; build ein cols 0..63
  {
    float acc2 = 0.f;
    const float* hbb = &hb[a * 68];
#pragma unroll
    for (int h = 0; h < HD; h += 4) {
      float4 hv = *(const float4*)(hbb + h);
      acc2 += se_w2[(h + 0) * DD + l16] * hv.x;
      acc2 += se_w2[(h + 1) * DD + l16] * hv.y;
      acc2 += se_w2[(h + 2) * DD + l16] * hv.z;
      acc2 += se_w2[(h + 3) * DD + l16] * hv.w;
    }
    float ev = acc2 + se_b2[l16];
    float sv = src[(size_t)(aB + a) * DD + l16] - smean[l16];
    ein[a * 160 + l16] = sv;
    ein[a * 160 + 16 + l16] = ev;
    ein[a * 160 + 32 + l16] = sv * ev;
    ein[a * 160 + 48 + l16] = sv - ev;
  }
  __syncthreads();

  // LN(159) in-place
  {
    float s1 = 0.f, sq = 0.f;
    float* eb = &ein[a * 160];
#pragma unroll
    for (int i = 0; i < 10; ++i) {
      int k = l16 * 10 + i;
      if (k < EHIN) { float v = eb[k]; s1 += v; sq += v * v; }
    }
    s1 += __shfl_xor(s1, 1); s1 += __shfl_xor(s1, 2); s1 += __shfl_xor(s1, 4); s1 += __shfl_xor(s1, 8);
    sq += __shfl_xor(sq, 1); sq += __shfl_xor(sq, 2); sq += __shfl_xor(sq, 4); sq += __shfl_xor(sq, 8);
    float m = s1 * (1.f / (float)EHIN);
    float var = sq * (1.f / (float)EHIN) - m * m;
    float inv = rsqrtf(var + 1e-5f);
#pragma unroll
    for (int i = 0; i < 10; ++i) {
      int k = l16 * 10 + i;
      if (k < EHIN)
        eb[k] = (eb[k] - m) * inv * eh_ln_g[k] + eh_ln_b[k];
    }
  }
  __syncthreads();

  // eh GEMM 159->64, dot with eh_w2, reduce
  {
    float acc[4] = {0.f, 0.f, 0.f, 0.f};
    const float* eb = &ein[a * 160];
#pragma unroll 4
    for (int k = 0; k < 156; k += 4) {
      float4 xa = *(const float4*)(eb + k);
      float4 wa = ((const float4*)(eh_w1 + (size_t)(k + 0) * HD))[l16];
      float4 wbv = ((const float4*)(eh_w1 + (size_t)(k + 1) * HD))[l16];
      float4 wc = ((const float4*)(eh_w1 + (size_t)(k + 2) * HD))[l16];
      float4 wd = ((const float4*)(eh_w1 + (size_t)(k + 3) * HD))[l16];
      acc[0] += wa.x * xa.x; acc[0] += wbv.x * xa.y; acc[0] += wc.x * xa.z; acc[0] += wd.x * xa.w;
      acc[1] += wa.y * xa.x; acc[1] += wbv.y * xa.y; acc[1] += wc.y * xa.z; acc[1] += wd.y * xa.w;
      acc[2] += wa.z * xa.x; acc[2] += wbv.z * xa.y; acc[2] += wc.z * xa.z; acc[2] += wd.z * xa.w;
      acc[3] += wa.w * xa.x; acc[3] += wbv.w * xa.y; acc[3] += wc.w * xa.z; acc[3] += wd.w * xa.w;
    }
#pragma unroll
    for (int k = 156; k < EHIN; ++k) {
      float xa = eb[k];
      float4 wa = ((const float4*)(eh_w1 + (size_t)k * HD))[l16];
      acc[0] += wa.x * xa; acc[1] += wa.y * xa; acc[2] += wa.z * xa; acc[3] += wa.w * xa;
    }
    float4 b1v = ((const float4*)eh_b1)[l16];
    float4 w2v = ((const float4*)eh_w2)[l16];
    float pa = silu_f(acc[0] + b1v.x) * w2v.x + silu_f(acc[1] + b1v.y) * w2v.y
             + silu_f(acc[2] + b1v.z) * w2v.z + silu_f(acc[3] + b1v.w) * w2v.w;
    pa += __shfl_xor(pa, 1); pa += __shfl_xor(pa, 2); pa += __shfl_xor(pa, 4); pa += __shfl_xor(pa, 8);
    pa += __shfl_xor(pa, 16); pa += __shfl_xor(pa, 32);  // sum wave's 4 atoms
    if (lane == 0) redv[wave] = pa + 4.f * eh_b2[0];
  }
  __syncthreads();
  if (t == 0) {
    float tot = redv[0] + redv[1] + redv[2] + redv[3];
    atomicAdd(&out[gph], tot * tanhf(far_gate[0]) * expf(energy_scale[0]));
  }
}

// ================================================================ launch
extern "C" void kernel_launch(void* const* d_in, const int* in_sizes, int n_in,
                              void* d_out, int out_size, void* d_ws, size_t ws_size,
                              hipStream_t stream) {
  const float* x         = (const float*)d_in[0];
  const float* pos       = (const float*)d_in[1];
  const float* in_ln_g   = (const float*)d_in[4];
  const float* in_ln_b   = (const float*)d_in[5];
  const float* src_w1    = (const float*)d_in[6];
  const float* src_b1    = (const float*)d_in[7];
  const float* src_w2    = (const float*)d_in[8];
  const float* src_b2    = (const float*)d_in[9];
  const float* src_ln_g  = (const float*)d_in[10];
  const float* src_ln_b  = (const float*)d_in[11];
  const float* se_ln_g   = (const float*)d_in[12];
  const float* se_ln_b   = (const float*)d_in[13];
  const float* se_w1     = (const float*)d_in[14];
  const float* se_b1     = (const float*)d_in[15];
  const float* se_w2     = (const float*)d_in[16];
  const float* se_b2     = (const float*)d_in[17];
  const float* eh_ln_g   = (const float*)d_in[18];
  const float* eh_ln_b   = (const float*)d_in[19];
  const float* eh_w1     = (const float*)d_in[20];
  const float* eh_b1     = (const float*)d_in[21];
  const float* eh_w2     = (const float*)d_in[22];
  const float* eh_b2     = (const float*)d_in[23];
  const float* k_screen  = (const float*)d_in[24];
  const float* kg_w1     = (const float*)d_in[25];
  const float* kg_b1     = (const float*)d_in[26];
  const float* kg_w2     = (const float*)d_in[27];
  const float* kg_b2     = (const float*)d_in[28];
  const float* far_gate  = (const float*)d_in[29];
  const float* en_scale  = (const float*)d_in[30];
  float* out = (float*)d_out;

  float* ws_src   = (float*)d_ws;                            // M*16
  float* ws_shell = ws_src + (size_t)M_AT * DD;              // M*95
  float* ws_part  = ws_shell + (size_t)M_AT * SEIN;          // 512*16
  float2* ws_lut  = (float2*)(ws_part + NFB * 16);           // NLUT float2

  k_front<<<NFB + 2, 256, 0, stream>>>(x, in_ln_g, in_ln_b, src_w1, src_b1,
                                       src_w2, src_b2, src_ln_g, src_ln_b,
                                       k_screen, kg_w1, kg_b1, kg_w2, kg_b2,
                                       ws_src, ws_part, ws_lut, out);
  k_pairs<<<B_G * (N_A / 4), 256, 0, stream>>>(pos, ws_src, ws_lut, ws_part, ws_shell);
  k_tail<<<M_AT / 16, 256, 0, stream>>>(ws_src, ws_shell, ws_part,
                                        se_ln_g, se_ln_b, se_w1, se_b1, se_w2, se_b2,
                                        eh_ln_g, eh_ln_b, eh_w1, eh_b1, eh_w2, eh_b2,
                                        far_gate, en_scale, out);
}